// Round 1
// baseline (144.068 us; speedup 1.0000x reference)
//
#include <hip/hip_runtime.h>
#include <math.h>

// Problem constants
#define B_     2
#define CIN    32
#define HH     512
#define WW     512
#define HID    768
#define SZ     16
#define NPATCH 1024      // 32x32 patch grid
#define KDIM   8192      // CIN*SZ*SZ
#define NCLS   21
#define LAT    128
#define LC     2688      // LAT*NCLS
#define NP     (B_ * NPATCH)   // 2048 patch rows

// prep-kernel block ranges
#define NB_W   6144      // HID*KDIM/4/256
#define NB_X   16384     // B_*CIN*HH*WW/4/256

typedef __attribute__((ext_vector_type(8))) short short8;   // 8 bf16 (4 VGPR)
typedef __attribute__((ext_vector_type(4))) float f32x4;

// RNE float->bf16
__device__ __forceinline__ ushort f2bf(float f) {
    union { float f; unsigned u; } v; v.f = f;
    unsigned r = (v.u + 0x7fff + ((v.u >> 16) & 1)) >> 16;
    return (ushort)r;
}
__device__ __forceinline__ float bf2f(ushort u) {
    union { unsigned u; float f; } v; v.u = (unsigned)u << 16;
    return v.f;
}

__device__ __forceinline__ void gload16(const void* g, void* l) {
    __builtin_amdgcn_global_load_lds(
        (const __attribute__((address_space(1))) unsigned int*)g,
        (__attribute__((address_space(3))) unsigned int*)l, 16, 0, 0);
}

// ---------------------------------------------------------------------------
// Fused prep kernel:
//   blocks [0, NB_W)                : conv_w f32 -> bf16 (layout already [HID][KDIM])
//   blocks [NB_W, NB_W+NB_X)        : x -> bf16 patch-major, dst-driven
//                                     (coalesced 512B/wave writes, 64B gather reads)
//   blocks [NB_W+NB_X, +NCLS)       : classlat[cls][d] = sum_u lat[u*21+cls][d]/(128*||lat||)
//                                     (norms computed inline, two-pass per block)
//   last block                      : zero gsum / gcnt for the fused final reduction
// ---------------------------------------------------------------------------
__global__ __launch_bounds__(256) void k_prep(const float* __restrict__ w,
                                              const float* __restrict__ x,
                                              const float* __restrict__ lat,
                                              ushort* __restrict__ wb,
                                              ushort* __restrict__ xb,
                                              float* __restrict__ classlat,
                                              float* __restrict__ gsum,
                                              unsigned* __restrict__ gcnt) {
    const int bid = blockIdx.x;
    const int t   = threadIdx.x;

    if (bid < NB_W) {
        // ---- conv_w convert (coalesced both sides) ----
        size_t i = ((size_t)bid * 256 + t) * 4;
        float4 v = *(const float4*)(w + i);
        ushort4 o;
        o.x = f2bf(v.x); o.y = f2bf(v.y); o.z = f2bf(v.z); o.w = f2bf(v.w);
        *(ushort4*)(wb + i) = o;
    } else if (bid < NB_W + NB_X) {
        // ---- x convert, dst-driven ----
        // e = dst ushort4 index; dst element d = e*4
        int e  = (bid - NB_W) * 256 + t;
        int p  = e >> 11;            // patch index (b,ph,pw)
        int o4 = e & 2047;           // within-patch element /4
        int c  = o4 >> 6;
        int i  = (o4 >> 2) & 15;
        int j0 = (o4 & 3) << 2;
        int b  = p >> 10, ph = (p >> 5) & 31, pw = p & 31;
        size_t src = (((size_t)(b * CIN + c) * HH + ph * 16 + i) * WW) + pw * 16 + j0;
        float4 v = *(const float4*)(x + src);
        ushort4 o;
        o.x = f2bf(v.x); o.y = f2bf(v.y); o.z = f2bf(v.z); o.w = f2bf(v.w);
        *(ushort4*)(xb + (size_t)e * 4) = o;   // 8B/lane, 512B/wave contiguous
    } else if (bid < NB_W + NB_X + NCLS) {
        // ---- classlat with inline row norms ----
        const int cls  = bid - (NB_W + NB_X);
        const int lane = t & 63, wv = t >> 6;
        __shared__ float sc_sh[LAT];

        // pass 1: wave wv computes norms of rows u in [wv*32, wv*32+32), 2 at a time
        for (int q = 0; q < 32; q += 2) {
            int u0 = wv * 32 + q;
            const float* r0 = lat + (size_t)(u0 * NCLS + cls) * HID;
            const float* r1 = lat + (size_t)((u0 + 1) * NCLS + cls) * HID;
            float s0 = 0.f, s1 = 0.f;
#pragma unroll
            for (int e = 0; e < HID / 64; ++e) {
                float a = r0[lane + e * 64]; s0 += a * a;
                float b = r1[lane + e * 64]; s1 += b * b;
            }
#pragma unroll
            for (int off = 32; off >= 1; off >>= 1) {
                s0 += __shfl_xor(s0, off, 64);
                s1 += __shfl_xor(s1, off, 64);
            }
            if (lane == 0) {
                sc_sh[u0]     = 1.0f / (128.0f * sqrtf(s0));
                sc_sh[u0 + 1] = 1.0f / (128.0f * sqrtf(s1));
            }
        }
        __syncthreads();

        // pass 2: weighted accumulate (rows L2-warm from pass 1)
        float a0 = 0.f, a1 = 0.f, a2 = 0.f;
#pragma unroll 4
        for (int u = 0; u < LAT; ++u) {
            float sc = sc_sh[u];
            const float* row = lat + (size_t)(u * NCLS + cls) * HID;
            a0 += row[t] * sc;
            a1 += row[t + 256] * sc;
            a2 += row[t + 512] * sc;
        }
        classlat[cls * HID + t]       = a0;
        classlat[cls * HID + t + 256] = a1;
        classlat[cls * HID + t + 512] = a2;
    } else {
        if (t == 0) { *gsum = 0.0f; *gcnt = 0u; }
    }
}

// ---------------------------------------------------------------------------
// MFMA GEMM: patch[p][d] = sum_k xb[p][k] * wb[d][k]   (B^T layout)
// 128x128 tile, BK=64, 4 waves (2x2) each 64x64 via 4x4 mfma_f32_16x16x32_bf16.
// T2 XOR swizzle via rule #21: linear LDS dest (global_load_lds) +
// inverse-swizzled GLOBAL source + swizzled ds_read.
// T1: bijective XCD-aware remap — each XCD owns one contiguous 96-block chunk
// (= one split-K slice at splitk=8): footprint 4MB xb + 1.5MB wb ~ per-XCD L2,
// by-fastest within the chunk so the wb slice stays resident.
// ---------------------------------------------------------------------------
template <int SPLITK>
__global__ __launch_bounds__(256) void k_gemm(const ushort* __restrict__ xb,
                                              const ushort* __restrict__ wb,
                                              ushort* __restrict__ pbuf) {
    constexpr int KS = KDIM / SPLITK;
    __shared__ ushort Als[128 * 64];   // [row][k] row-major, 16 KB
    __shared__ ushort Bls[128 * 64];

    // ---- T1 remap: flat launch id -> (bx, by, bz) ----
    // nwg = 96*SPLITK is always divisible by 8, so xcd*(nwg/8)+flat/8 is bijective.
    const int flat = blockIdx.x + 16 * (blockIdx.y + 6 * blockIdx.z);
    constexpr int nwg = 96 * SPLITK;
    const int wg = (flat & 7) * (nwg >> 3) + (flat >> 3);
    const int bz = wg / 96;
    const int rr = wg - bz * 96;
    const int by = rr % 6;       // by-fastest: consecutive blocks share the xb panel,
    const int bx = rr / 6;       // stream the 1.5MB wb slice (stays in L2)

    const int tid  = threadIdx.x;
    const int wv   = tid >> 6;
    const int lane = tid & 63;
    const int wm   = (wv >> 1) * 64;   // wave row offset in tile
    const int wn   = (wv & 1) * 64;    // wave col offset in tile

    const size_t abase = ((size_t)bx * 128) * KDIM + (size_t)bz * KS;
    const size_t bbase = ((size_t)by * 128) * KDIM + (size_t)bz * KS;

    const int srow  = wv * 8 + (lane >> 3);                    // + q*32
    const int skoff = (((lane & 7) ^ (lane >> 3)) * 8);        // swizzled source elem

    f32x4 acc[4][4];
#pragma unroll
    for (int m = 0; m < 4; ++m)
#pragma unroll
        for (int n = 0; n < 4; ++n) acc[m][n] = (f32x4)(0.f);

    const int fr = lane & 15, fq = lane >> 4;
    const int frx = (fr & 7) * 8;   // read-side XOR (elements)

    for (int kk = 0; kk < KS; kk += 64) {
#pragma unroll
        for (int q = 0; q < 4; ++q) {
            const int row = q * 32 + srow;
            gload16(&xb[abase + (size_t)row * KDIM + kk + skoff], &Als[q * 2048 + wv * 512]);
            gload16(&wb[bbase + (size_t)row * KDIM + kk + skoff], &Bls[q * 2048 + wv * 512]);
        }
        __syncthreads();   // drains vmcnt: tiles ready

#pragma unroll
        for (int s = 0; s < 2; ++s) {
            short8 af[4], bf[4];
#pragma unroll
            for (int m = 0; m < 4; ++m)
                af[m] = *(const short8*)&Als[(wm + m * 16 + fr) * 64 + ((s * 32 + fq * 8) ^ frx)];
#pragma unroll
            for (int n = 0; n < 4; ++n)
                bf[n] = *(const short8*)&Bls[(wn + n * 16 + fr) * 64 + ((s * 32 + fq * 8) ^ frx)];
#pragma unroll
            for (int m = 0; m < 4; ++m)
#pragma unroll
                for (int n = 0; n < 4; ++n)
                    acc[m][n] = __builtin_amdgcn_mfma_f32_16x16x32_bf16(af[m], bf[n], acc[m][n], 0, 0, 0);
        }
        __syncthreads();   // compute done before next-iter overwrite
    }

    ushort* outz = pbuf + (size_t)bz * ((size_t)NP * HID);
#pragma unroll
    for (int m = 0; m < 4; ++m) {
#pragma unroll
        for (int n = 0; n < 4; ++n) {
            int col = by * 128 + wn + n * 16 + fr;
#pragma unroll
            for (int j = 0; j < 4; ++j) {
                int row = bx * 128 + wm + m * 16 + fq * 4 + j;
                outz[(size_t)row * HID + col] = f2bf(acc[m][n][j]);
            }
        }
    }
}

// ---------------------------------------------------------------------------
// Per-patch epilogue + fused global reduction:
// sum split-K bf16 partials + bias -> norm -> 21 dots -> masked exp(2*sim)
// -> atomicAdd into gsum; last block writes -log(gsum).
// ---------------------------------------------------------------------------
template <int SPLITK>
__global__ __launch_bounds__(256) void k_final(const ushort* __restrict__ pbuf,
                                               const float* __restrict__ conv_b,
                                               const float* __restrict__ classlat,
                                               const int* __restrict__ mask,
                                               float* __restrict__ gsum,
                                               unsigned* __restrict__ gcnt,
                                               float* __restrict__ out) {
    const int p = blockIdx.x;        // 0..2047
    const int b = p >> 10, n = p & 1023;
    const int t = threadIdx.x;
    const int lane = t & 63, wv = t >> 6;

    float f0 = conv_b[t], f1 = conv_b[t + 256], f2 = conv_b[t + 512];
    {
        const size_t base = (size_t)p * HID;
#pragma unroll
        for (int zz = 0; zz < SPLITK; ++zz) {
            const ushort* pz = pbuf + (size_t)zz * ((size_t)NP * HID) + base;
            f0 += bf2f(pz[t]);
            f1 += bf2f(pz[t + 256]);
            f2 += bf2f(pz[t + 512]);
        }
    }

    __shared__ float wsum[4];
    __shared__ float wdot[4][NCLS];
    __shared__ float cpart[NCLS];

    float ss = f0 * f0 + f1 * f1 + f2 * f2;
#pragma unroll
    for (int off = 32; off >= 1; off >>= 1) ss += __shfl_xor(ss, off, 64);
    if (lane == 0) wsum[wv] = ss;

    float dots[NCLS];
#pragma unroll
    for (int c = 0; c < NCLS; ++c) {
        const float* cl = classlat + c * HID;
        dots[c] = cl[t] * f0 + cl[t + 256] * f1 + cl[t + 512] * f2;
    }
#pragma unroll
    for (int c = 0; c < NCLS; ++c) {
        float v = dots[c];
#pragma unroll
        for (int off = 32; off >= 1; off >>= 1) v += __shfl_xor(v, off, 64);
        if (lane == 0) wdot[wv][c] = v;
    }
    __syncthreads();

    if (t < NCLS) {
        float tot  = wsum[0] + wsum[1] + wsum[2] + wsum[3];
        float invn = 1.0f / sqrtf(tot);
        float dot  = wdot[0][t] + wdot[1][t] + wdot[2][t] + wdot[3][t];
        float sim  = dot * invn;
        int   mv   = mask[(size_t)(b * NCLS + t) * NPATCH + n];
        cpart[t]   = (mv != 0) ? expf(sim * 2.0f) : 0.0f;
    }
    __syncthreads();
    if (t == 0) {
        float s = 0.f;
#pragma unroll
        for (int c = 0; c < NCLS; ++c) s += cpart[c];
        atomicAdd(gsum, s);
        __threadfence();
        unsigned prev = atomicAdd(gcnt, 1u);
        if (prev == NP - 1) {
            out[0] = -logf(atomicAdd(gsum, 0.0f));
        }
    }
}

// ---------------------------------------------------------------------------
extern "C" void kernel_launch(void* const* d_in, const int* in_sizes, int n_in,
                              void* d_out, int out_size, void* d_ws, size_t ws_size,
                              hipStream_t stream) {
    const float* x      = (const float*)d_in[0];
    const int*   mask   = (const int*)d_in[1];
    const float* conv_w = (const float*)d_in[2];
    const float* conv_b = (const float*)d_in[3];
    const float* latent = (const float*)d_in[4];
    float* out = (float*)d_out;

    // workspace layout (bytes)
    const size_t xb_bytes   = (size_t)NP * KDIM * 2;        // 33,554,432
    const size_t wb_bytes   = (size_t)HID * KDIM * 2;       // 12,582,912
    const size_t pslice     = (size_t)NP * HID * 2;         // 3,145,728 (bf16)
    const size_t small_need = (size_t)NCLS * HID * 4 + 256;

    char* base = (char*)d_ws;
    ushort* xb   = (ushort*)base;
    ushort* wb   = (ushort*)(base + xb_bytes);
    ushort* pbuf = (ushort*)(base + xb_bytes + wb_bytes);

    int splitk = 1;
    const size_t fixed = xb_bytes + wb_bytes + small_need;
    if (ws_size >= fixed + 8 * pslice)      splitk = 8;
    else if (ws_size >= fixed + 4 * pslice) splitk = 4;
    else if (ws_size >= fixed + 2 * pslice) splitk = 2;

    float*    classlat = (float*)(base + xb_bytes + wb_bytes + (size_t)splitk * pslice);
    float*    gsum     = classlat + NCLS * HID;
    unsigned* gcnt     = (unsigned*)(gsum + 1);

    k_prep<<<NB_W + NB_X + NCLS + 1, 256, 0, stream>>>(conv_w, x, latent, wb, xb,
                                                       classlat, gsum, gcnt);

    dim3 g(NP / 128, HID / 128, splitk);
    switch (splitk) {
        case 8: k_gemm<8><<<g, 256, 0, stream>>>(xb, wb, pbuf); break;
        case 4: k_gemm<4><<<g, 256, 0, stream>>>(xb, wb, pbuf); break;
        case 2: k_gemm<2><<<g, 256, 0, stream>>>(xb, wb, pbuf); break;
        default: k_gemm<1><<<g, 256, 0, stream>>>(xb, wb, pbuf); break;
    }

    switch (splitk) {
        case 8: k_final<8><<<NP, 256, 0, stream>>>(pbuf, conv_b, classlat, mask, gsum, gcnt, out); break;
        case 4: k_final<4><<<NP, 256, 0, stream>>>(pbuf, conv_b, classlat, mask, gsum, gcnt, out); break;
        case 2: k_final<2><<<NP, 256, 0, stream>>>(pbuf, conv_b, classlat, mask, gsum, gcnt, out); break;
        default: k_final<1><<<NP, 256, 0, stream>>>(pbuf, conv_b, classlat, mask, gsum, gcnt, out); break;
    }
}

// Round 2
// 96.901 us; speedup vs baseline: 1.4868x; 1.4868x over previous
//
#include <hip/hip_runtime.h>
#include <math.h>

// Problem constants
#define B_     2
#define CIN    32
#define HH     512
#define WW     512
#define HID    768
#define SZ     16
#define NPATCH 1024      // 32x32 patch grid
#define KDIM   8192      // CIN*SZ*SZ
#define NCLS   21
#define LAT    128
#define LC     2688      // LAT*NCLS
#define NP     (B_ * NPATCH)   // 2048 patch rows

// prep-kernel block ranges
#define NB_W   6144      // HID*KDIM/4/256
#define NB_X   16384     // B_*CIN*HH*WW/4/256

typedef __attribute__((ext_vector_type(8))) short short8;   // 8 bf16 (4 VGPR)
typedef __attribute__((ext_vector_type(4))) float f32x4;

// RNE float->bf16
__device__ __forceinline__ ushort f2bf(float f) {
    union { float f; unsigned u; } v; v.f = f;
    unsigned r = (v.u + 0x7fff + ((v.u >> 16) & 1)) >> 16;
    return (ushort)r;
}
__device__ __forceinline__ float bf2f(ushort u) {
    union { unsigned u; float f; } v; v.u = (unsigned)u << 16;
    return v.f;
}

__device__ __forceinline__ void gload16(const void* g, void* l) {
    __builtin_amdgcn_global_load_lds(
        (const __attribute__((address_space(1))) unsigned int*)g,
        (__attribute__((address_space(3))) unsigned int*)l, 16, 0, 0);
}

// ---------------------------------------------------------------------------
// Fused prep kernel:
//   blocks [0, NB_W)         : conv_w f32 -> bf16
//   blocks [NB_W, NB_W+NB_X) : x -> bf16 patch-major, dst-driven
//   blocks [.., +NCLS)       : classlat[cls][d] = sum_u lat[u*21+cls][d]/(128*||lat||)
// ---------------------------------------------------------------------------
__global__ __launch_bounds__(256) void k_prep(const float* __restrict__ w,
                                              const float* __restrict__ x,
                                              const float* __restrict__ lat,
                                              ushort* __restrict__ wb,
                                              ushort* __restrict__ xb,
                                              float* __restrict__ classlat) {
    const int bid = blockIdx.x;
    const int t   = threadIdx.x;

    if (bid < NB_W) {
        // ---- conv_w convert (coalesced both sides) ----
        size_t i = ((size_t)bid * 256 + t) * 4;
        float4 v = *(const float4*)(w + i);
        ushort4 o;
        o.x = f2bf(v.x); o.y = f2bf(v.y); o.z = f2bf(v.z); o.w = f2bf(v.w);
        *(ushort4*)(wb + i) = o;
    } else if (bid < NB_W + NB_X) {
        // ---- x convert, dst-driven ----
        int e  = (bid - NB_W) * 256 + t;
        int p  = e >> 11;            // patch index (b,ph,pw)
        int o4 = e & 2047;           // within-patch element /4
        int c  = o4 >> 6;
        int i  = (o4 >> 2) & 15;
        int j0 = (o4 & 3) << 2;
        int b  = p >> 10, ph = (p >> 5) & 31, pw = p & 31;
        size_t src = (((size_t)(b * CIN + c) * HH + ph * 16 + i) * WW) + pw * 16 + j0;
        float4 v = *(const float4*)(x + src);
        ushort4 o;
        o.x = f2bf(v.x); o.y = f2bf(v.y); o.z = f2bf(v.z); o.w = f2bf(v.w);
        *(ushort4*)(xb + (size_t)e * 4) = o;   // 8B/lane, 512B/wave contiguous
    } else {
        // ---- classlat with inline row norms ----
        const int cls  = bid - (NB_W + NB_X);
        const int lane = t & 63, wv = t >> 6;
        __shared__ float sc_sh[LAT];

        for (int q = 0; q < 32; q += 2) {
            int u0 = wv * 32 + q;
            const float* r0 = lat + (size_t)(u0 * NCLS + cls) * HID;
            const float* r1 = lat + (size_t)((u0 + 1) * NCLS + cls) * HID;
            float s0 = 0.f, s1 = 0.f;
#pragma unroll
            for (int e = 0; e < HID / 64; ++e) {
                float a = r0[lane + e * 64]; s0 += a * a;
                float b = r1[lane + e * 64]; s1 += b * b;
            }
#pragma unroll
            for (int off = 32; off >= 1; off >>= 1) {
                s0 += __shfl_xor(s0, off, 64);
                s1 += __shfl_xor(s1, off, 64);
            }
            if (lane == 0) {
                sc_sh[u0]     = 1.0f / (128.0f * sqrtf(s0));
                sc_sh[u0 + 1] = 1.0f / (128.0f * sqrtf(s1));
            }
        }
        __syncthreads();

        float a0 = 0.f, a1 = 0.f, a2 = 0.f;
#pragma unroll 4
        for (int u = 0; u < LAT; ++u) {
            float sc = sc_sh[u];
            const float* row = lat + (size_t)(u * NCLS + cls) * HID;
            a0 += row[t] * sc;
            a1 += row[t + 256] * sc;
            a2 += row[t + 512] * sc;
        }
        classlat[cls * HID + t]       = a0;
        classlat[cls * HID + t + 256] = a1;
        classlat[cls * HID + t + 512] = a2;
    }
}

// ---------------------------------------------------------------------------
// MFMA GEMM: patch[p][d] = sum_k xb[p][k] * wb[d][k]   (B^T layout)
// 128x128 tile, BK=64, 4 waves (2x2) each 64x64 via 4x4 mfma_f32_16x16x32_bf16.
// T2 XOR swizzle (rule #21): linear LDS dest + inverse-swizzled global source
// + swizzled ds_read.  T1 bijective XCD remap: each XCD owns one split-K slice.
// Output layout: pbuf[p][z][d]  (per-patch split-K partials contiguous, 16B-aligned)
// ---------------------------------------------------------------------------
template <int SPLITK>
__global__ __launch_bounds__(256) void k_gemm(const ushort* __restrict__ xb,
                                              const ushort* __restrict__ wb,
                                              ushort* __restrict__ pbuf) {
    constexpr int KS = KDIM / SPLITK;
    __shared__ ushort Als[128 * 64];   // [row][k] row-major, 16 KB
    __shared__ ushort Bls[128 * 64];

    // ---- T1 remap ----
    const int flat = blockIdx.x + 16 * (blockIdx.y + 6 * blockIdx.z);
    constexpr int nwg = 96 * SPLITK;
    const int wg = (flat & 7) * (nwg >> 3) + (flat >> 3);
    const int bz = wg / 96;
    const int rr = wg - bz * 96;
    const int by = rr % 6;
    const int bx = rr / 6;

    const int tid  = threadIdx.x;
    const int wv   = tid >> 6;
    const int lane = tid & 63;
    const int wm   = (wv >> 1) * 64;
    const int wn   = (wv & 1) * 64;

    const size_t abase = ((size_t)bx * 128) * KDIM + (size_t)bz * KS;
    const size_t bbase = ((size_t)by * 128) * KDIM + (size_t)bz * KS;

    const int srow  = wv * 8 + (lane >> 3);                    // + q*32
    const int skoff = (((lane & 7) ^ (lane >> 3)) * 8);        // swizzled source elem

    f32x4 acc[4][4];
#pragma unroll
    for (int m = 0; m < 4; ++m)
#pragma unroll
        for (int n = 0; n < 4; ++n) acc[m][n] = (f32x4)(0.f);

    const int fr = lane & 15, fq = lane >> 4;
    const int frx = (fr & 7) * 8;   // read-side XOR (elements)

    for (int kk = 0; kk < KS; kk += 64) {
#pragma unroll
        for (int q = 0; q < 4; ++q) {
            const int row = q * 32 + srow;
            gload16(&xb[abase + (size_t)row * KDIM + kk + skoff], &Als[q * 2048 + wv * 512]);
            gload16(&wb[bbase + (size_t)row * KDIM + kk + skoff], &Bls[q * 2048 + wv * 512]);
        }
        __syncthreads();   // drains vmcnt: tiles ready

#pragma unroll
        for (int s = 0; s < 2; ++s) {
            short8 af[4], bf[4];
#pragma unroll
            for (int m = 0; m < 4; ++m)
                af[m] = *(const short8*)&Als[(wm + m * 16 + fr) * 64 + ((s * 32 + fq * 8) ^ frx)];
#pragma unroll
            for (int n = 0; n < 4; ++n)
                bf[n] = *(const short8*)&Bls[(wn + n * 16 + fr) * 64 + ((s * 32 + fq * 8) ^ frx)];
#pragma unroll
            for (int m = 0; m < 4; ++m)
#pragma unroll
                for (int n = 0; n < 4; ++n)
                    acc[m][n] = __builtin_amdgcn_mfma_f32_16x16x32_bf16(af[m], bf[n], acc[m][n], 0, 0, 0);
        }
        __syncthreads();
    }

#pragma unroll
    for (int m = 0; m < 4; ++m) {
#pragma unroll
        for (int n = 0; n < 4; ++n) {
            int col = by * 128 + wn + n * 16 + fr;
#pragma unroll
            for (int j = 0; j < 4; ++j) {
                int row = bx * 128 + wm + m * 16 + fq * 4 + j;
                pbuf[((size_t)row * SPLITK + bz) * HID + col] = f2bf(acc[m][n][j]);
            }
        }
    }
}

// ---------------------------------------------------------------------------
// Per-patch epilogue: stage the patch's contiguous [SPLITK][HID] bf16 partials
// into LDS (coalesced 16B loads), sum + bias -> norm -> 21 dots ->
// masked exp(2*sim) -> partial[p].  (Global reduce stays a separate tiny
// kernel: 2048 same-address device atomics cost ~40us — measured round 1.)
// ---------------------------------------------------------------------------
template <int SPLITK>
__global__ __launch_bounds__(256) void k_final(const ushort* __restrict__ pbuf,
                                               const float* __restrict__ conv_b,
                                               const float* __restrict__ classlat,
                                               const int* __restrict__ mask,
                                               float* __restrict__ partial) {
    const int p = blockIdx.x;        // 0..2047
    const int b = p >> 10, n = p & 1023;
    const int t = threadIdx.x;
    const int lane = t & 63, wv = t >> 6;

    __shared__ ushort sh[SPLITK * HID];
    const ushort* pb = pbuf + (size_t)p * (SPLITK * HID);
    for (int i = t; i < SPLITK * HID / 8; i += 256)
        *(short8*)&sh[i * 8] = *(const short8*)&pb[(size_t)i * 8];
    __syncthreads();

    float f0 = conv_b[t], f1 = conv_b[t + 256], f2 = conv_b[t + 512];
#pragma unroll
    for (int z = 0; z < SPLITK; ++z) {
        f0 += bf2f(sh[z * HID + t]);
        f1 += bf2f(sh[z * HID + t + 256]);
        f2 += bf2f(sh[z * HID + t + 512]);
    }

    __shared__ float wsum[4];
    __shared__ float wdot[4][NCLS];
    __shared__ float cpart[NCLS];

    float ss = f0 * f0 + f1 * f1 + f2 * f2;
#pragma unroll
    for (int off = 32; off >= 1; off >>= 1) ss += __shfl_xor(ss, off, 64);
    if (lane == 0) wsum[wv] = ss;

    float dots[NCLS];
#pragma unroll
    for (int c = 0; c < NCLS; ++c) {
        const float* cl = classlat + c * HID;
        dots[c] = cl[t] * f0 + cl[t + 256] * f1 + cl[t + 512] * f2;
    }
#pragma unroll
    for (int c = 0; c < NCLS; ++c) {
        float v = dots[c];
#pragma unroll
        for (int off = 32; off >= 1; off >>= 1) v += __shfl_xor(v, off, 64);
        if (lane == 0) wdot[wv][c] = v;
    }
    __syncthreads();

    if (t < NCLS) {
        float tot  = wsum[0] + wsum[1] + wsum[2] + wsum[3];
        float invn = 1.0f / sqrtf(tot);
        float dot  = wdot[0][t] + wdot[1][t] + wdot[2][t] + wdot[3][t];
        float sim  = dot * invn;
        int   mv   = mask[(size_t)(b * NCLS + t) * NPATCH + n];
        cpart[t]   = (mv != 0) ? expf(sim * 2.0f) : 0.0f;
    }
    __syncthreads();
    if (t == 0) {
        float s = 0.f;
#pragma unroll
        for (int c = 0; c < NCLS; ++c) s += cpart[c];
        partial[p] = s;
    }
}

__global__ __launch_bounds__(256) void k_reduce(const float* __restrict__ partial,
                                                float* __restrict__ out) {
    int t = threadIdx.x;
    float s = 0.f;
    for (int i = t; i < NP; i += 256) s += partial[i];
#pragma unroll
    for (int off = 32; off >= 1; off >>= 1) s += __shfl_xor(s, off, 64);
    __shared__ float ws[4];
    if ((t & 63) == 0) ws[t >> 6] = s;
    __syncthreads();
    if (t == 0) out[0] = -logf(ws[0] + ws[1] + ws[2] + ws[3]);
}

// ---------------------------------------------------------------------------
extern "C" void kernel_launch(void* const* d_in, const int* in_sizes, int n_in,
                              void* d_out, int out_size, void* d_ws, size_t ws_size,
                              hipStream_t stream) {
    const float* x      = (const float*)d_in[0];
    const int*   mask   = (const int*)d_in[1];
    const float* conv_w = (const float*)d_in[2];
    const float* conv_b = (const float*)d_in[3];
    const float* latent = (const float*)d_in[4];
    float* out = (float*)d_out;

    // workspace layout (bytes)
    const size_t xb_bytes   = (size_t)NP * KDIM * 2;        // 33,554,432
    const size_t wb_bytes   = (size_t)HID * KDIM * 2;       // 12,582,912
    const size_t pslice     = (size_t)NP * HID * 2;         // 3,145,728 (bf16)
    const size_t small_need = (size_t)NCLS * HID * 4 + NP * 4 + 256;

    char* base = (char*)d_ws;
    ushort* xb   = (ushort*)base;
    ushort* wb   = (ushort*)(base + xb_bytes);
    ushort* pbuf = (ushort*)(base + xb_bytes + wb_bytes);

    int splitk = 1;
    const size_t fixed = xb_bytes + wb_bytes + small_need;
    if (ws_size >= fixed + 8 * pslice)      splitk = 8;
    else if (ws_size >= fixed + 4 * pslice) splitk = 4;
    else if (ws_size >= fixed + 2 * pslice) splitk = 2;

    float* classlat = (float*)(base + xb_bytes + wb_bytes + (size_t)splitk * pslice);
    float* partial  = classlat + NCLS * HID;

    k_prep<<<NB_W + NB_X + NCLS, 256, 0, stream>>>(conv_w, x, latent, wb, xb, classlat);

    dim3 g(NP / 128, HID / 128, splitk);
    switch (splitk) {
        case 8: k_gemm<8><<<g, 256, 0, stream>>>(xb, wb, pbuf); break;
        case 4: k_gemm<4><<<g, 256, 0, stream>>>(xb, wb, pbuf); break;
        case 2: k_gemm<2><<<g, 256, 0, stream>>>(xb, wb, pbuf); break;
        default: k_gemm<1><<<g, 256, 0, stream>>>(xb, wb, pbuf); break;
    }

    switch (splitk) {
        case 8: k_final<8><<<NP, 256, 0, stream>>>(pbuf, conv_b, classlat, mask, partial); break;
        case 4: k_final<4><<<NP, 256, 0, stream>>>(pbuf, conv_b, classlat, mask, partial); break;
        case 2: k_final<2><<<NP, 256, 0, stream>>>(pbuf, conv_b, classlat, mask, partial); break;
        default: k_final<1><<<NP, 256, 0, stream>>>(pbuf, conv_b, classlat, mask, partial); break;
    }
    k_reduce<<<1, 256, 0, stream>>>(partial, out);
}

// Round 3
// 95.840 us; speedup vs baseline: 1.5032x; 1.0111x over previous
//
#include <hip/hip_runtime.h>
#include <math.h>

// Problem constants
#define B_     2
#define CIN    32
#define HH     512
#define WW     512
#define HID    768
#define SZ     16
#define NPATCH 1024      // 32x32 patch grid
#define KDIM   8192      // CIN*SZ*SZ
#define NCLS   21
#define LAT    128
#define LC     2688      // LAT*NCLS
#define NP     (B_ * NPATCH)   // 2048 patch rows

// prep-kernel block ranges
#define NB_W4  1536      // HID*KDIM/16/256  (4 float4 per thread)
#define NB_XT  2048      // B_*CIN*(HH/16)   one block per (b,c,ph) = 32KB chunk

typedef __attribute__((ext_vector_type(8))) short short8;   // 8 bf16 (4 VGPR)
typedef __attribute__((ext_vector_type(4))) float f32x4;

// RNE float->bf16
__device__ __forceinline__ ushort f2bf(float f) {
    union { float f; unsigned u; } v; v.f = f;
    unsigned r = (v.u + 0x7fff + ((v.u >> 16) & 1)) >> 16;
    return (ushort)r;
}
__device__ __forceinline__ float bf2f(ushort u) {
    union { unsigned u; float f; } v; v.u = (unsigned)u << 16;
    return v.f;
}

__device__ __forceinline__ void gload16(const void* g, void* l) {
    __builtin_amdgcn_global_load_lds(
        (const __attribute__((address_space(1))) unsigned int*)g,
        (__attribute__((address_space(3))) unsigned int*)l, 16, 0, 0);
}

// ---------------------------------------------------------------------------
// Fused prep kernel:
//   blocks [0, NB_W4)          : conv_w f32 -> bf16 (4 float4/thread, both coalesced)
//   blocks [NB_W4, +NB_XT)     : x -> bf16 patch-major via LDS transpose.
//       One block per (b,c,ph): read 16 contiguous image rows (32KB, fully
//       coalesced float4), stage in padded LDS [32][264], write 32 dense
//       512B segments (short8) to xb.  Both sides coalesced — the round-2
//       dst-driven version read scattered 64B segments (57us, 1.7TB/s).
//   blocks [.., +NCLS)         : classlat[cls][d] = sum_u lat[u*21+cls][d]/(128*||lat||)
// ---------------------------------------------------------------------------
__global__ __launch_bounds__(256) void k_prep(const float* __restrict__ w,
                                              const float* __restrict__ x,
                                              const float* __restrict__ lat,
                                              ushort* __restrict__ wb,
                                              ushort* __restrict__ xb,
                                              float* __restrict__ classlat) {
    const int bid = blockIdx.x;
    const int t   = threadIdx.x;

    if (bid < NB_W4) {
        // ---- conv_w convert (coalesced both sides) ----
#pragma unroll
        for (int k = 0; k < 4; ++k) {
            size_t i = ((size_t)bid * 1024 + k * 256 + t) * 4;
            float4 v = *(const float4*)(w + i);
            ushort4 o;
            o.x = f2bf(v.x); o.y = f2bf(v.y); o.z = f2bf(v.z); o.w = f2bf(v.w);
            *(ushort4*)(wb + i) = o;
        }
    } else if (bid < NB_W4 + NB_XT) {
        // ---- x convert via LDS transpose ----
        __shared__ ushort sh[32 * 264];   // [pw][256+8 pad] — stride 528B ≡ 4 mod 32 dwords
        const int cvb = bid - NB_W4;
        const int b  = cvb >> 10;
        const int c  = (cvb >> 5) & 31;
        const int ph = cvb & 31;
        const float* src = x + (((size_t)(b * CIN + c) * HH) + (size_t)ph * 16) * WW;

#pragma unroll
        for (int q = 0; q < 8; ++q) {
            int f  = q * 256 + t;        // [0, 2048) = 16 rows x 128 float4
            int i  = f >> 7;             // row in patch strip
            int w4 = f & 127;            // float4 index within row
            float4 v = *(const float4*)(src + (size_t)i * WW + w4 * 4);
            int pw = w4 >> 2, j0 = (w4 & 3) * 4;
            ushort4 o;
            o.x = f2bf(v.x); o.y = f2bf(v.y); o.z = f2bf(v.z); o.w = f2bf(v.w);
            *(ushort4*)&sh[pw * 264 + i * 16 + j0] = o;
        }
        __syncthreads();

        // write out: 32 patches x 256 elems (512B dense segments)
        ushort* dst = xb + ((size_t)(b * 1024 + ph * 32) << 13) + c * 256;
#pragma unroll
        for (int q = 0; q < 4; ++q) {
            int s  = q * 256 + t;        // [0, 1024) short8 stores
            int pw = s >> 5;
            int o8 = (s & 31) * 8;
            short8 v = *(const short8*)&sh[pw * 264 + o8];
            *(short8*)&dst[((size_t)pw << 13) + o8] = v;
        }
    } else {
        // ---- classlat with inline row norms ----
        const int cls  = bid - (NB_W4 + NB_XT);
        const int lane = t & 63, wv = t >> 6;
        __shared__ float sc_sh[LAT];

        for (int q = 0; q < 32; q += 2) {
            int u0 = wv * 32 + q;
            const float* r0 = lat + (size_t)(u0 * NCLS + cls) * HID;
            const float* r1 = lat + (size_t)((u0 + 1) * NCLS + cls) * HID;
            float s0 = 0.f, s1 = 0.f;
#pragma unroll
            for (int e = 0; e < HID / 64; ++e) {
                float a = r0[lane + e * 64]; s0 += a * a;
                float b2 = r1[lane + e * 64]; s1 += b2 * b2;
            }
#pragma unroll
            for (int off = 32; off >= 1; off >>= 1) {
                s0 += __shfl_xor(s0, off, 64);
                s1 += __shfl_xor(s1, off, 64);
            }
            if (lane == 0) {
                sc_sh[u0]     = 1.0f / (128.0f * sqrtf(s0));
                sc_sh[u0 + 1] = 1.0f / (128.0f * sqrtf(s1));
            }
        }
        __syncthreads();

        float a0 = 0.f, a1 = 0.f, a2 = 0.f;
#pragma unroll 4
        for (int u = 0; u < LAT; ++u) {
            float sc = sc_sh[u];
            const float* row = lat + (size_t)(u * NCLS + cls) * HID;
            a0 += row[t] * sc;
            a1 += row[t + 256] * sc;
            a2 += row[t + 512] * sc;
        }
        classlat[cls * HID + t]       = a0;
        classlat[cls * HID + t + 256] = a1;
        classlat[cls * HID + t + 512] = a2;
    }
}

// ---------------------------------------------------------------------------
// MFMA GEMM: patch[p][d] = sum_k xb[p][k] * wb[d][k]   (B^T layout)
// 128x128 tile, BK=64, 4 waves (2x2) each 64x64 via 4x4 mfma_f32_16x16x32_bf16.
// T2 XOR swizzle (rule #21): linear LDS dest + inverse-swizzled global source
// + swizzled ds_read.  T1 bijective XCD remap: each XCD owns one split-K slice.
// Output layout: pbuf[p][z][d]  (per-patch split-K partials contiguous)
// ---------------------------------------------------------------------------
template <int SPLITK>
__global__ __launch_bounds__(256) void k_gemm(const ushort* __restrict__ xb,
                                              const ushort* __restrict__ wb,
                                              ushort* __restrict__ pbuf) {
    constexpr int KS = KDIM / SPLITK;
    __shared__ ushort Als[128 * 64];   // [row][k] row-major, 16 KB
    __shared__ ushort Bls[128 * 64];

    // ---- T1 remap ----
    const int flat = blockIdx.x + 16 * (blockIdx.y + 6 * blockIdx.z);
    constexpr int nwg = 96 * SPLITK;
    const int wg = (flat & 7) * (nwg >> 3) + (flat >> 3);
    const int bz = wg / 96;
    const int rr = wg - bz * 96;
    const int by = rr % 6;
    const int bx = rr / 6;

    const int tid  = threadIdx.x;
    const int wv   = tid >> 6;
    const int lane = tid & 63;
    const int wm   = (wv >> 1) * 64;
    const int wn   = (wv & 1) * 64;

    const size_t abase = ((size_t)bx * 128) * KDIM + (size_t)bz * KS;
    const size_t bbase = ((size_t)by * 128) * KDIM + (size_t)bz * KS;

    const int srow  = wv * 8 + (lane >> 3);                    // + q*32
    const int skoff = (((lane & 7) ^ (lane >> 3)) * 8);        // swizzled source elem

    f32x4 acc[4][4];
#pragma unroll
    for (int m = 0; m < 4; ++m)
#pragma unroll
        for (int n = 0; n < 4; ++n) acc[m][n] = (f32x4)(0.f);

    const int fr = lane & 15, fq = lane >> 4;
    const int frx = (fr & 7) * 8;   // read-side XOR (elements)

    for (int kk = 0; kk < KS; kk += 64) {
#pragma unroll
        for (int q = 0; q < 4; ++q) {
            const int row = q * 32 + srow;
            gload16(&xb[abase + (size_t)row * KDIM + kk + skoff], &Als[q * 2048 + wv * 512]);
            gload16(&wb[bbase + (size_t)row * KDIM + kk + skoff], &Bls[q * 2048 + wv * 512]);
        }
        __syncthreads();   // drains vmcnt: tiles ready

#pragma unroll
        for (int s = 0; s < 2; ++s) {
            short8 af[4], bf[4];
#pragma unroll
            for (int m = 0; m < 4; ++m)
                af[m] = *(const short8*)&Als[(wm + m * 16 + fr) * 64 + ((s * 32 + fq * 8) ^ frx)];
#pragma unroll
            for (int n = 0; n < 4; ++n)
                bf[n] = *(const short8*)&Bls[(wn + n * 16 + fr) * 64 + ((s * 32 + fq * 8) ^ frx)];
#pragma unroll
            for (int m = 0; m < 4; ++m)
#pragma unroll
                for (int n = 0; n < 4; ++n)
                    acc[m][n] = __builtin_amdgcn_mfma_f32_16x16x32_bf16(af[m], bf[n], acc[m][n], 0, 0, 0);
        }
        __syncthreads();
    }

#pragma unroll
    for (int m = 0; m < 4; ++m) {
#pragma unroll
        for (int n = 0; n < 4; ++n) {
            int col = by * 128 + wn + n * 16 + fr;
#pragma unroll
            for (int j = 0; j < 4; ++j) {
                int row = bx * 128 + wm + m * 16 + fq * 4 + j;
                pbuf[((size_t)row * SPLITK + bz) * HID + col] = f2bf(acc[m][n][j]);
            }
        }
    }
}

// ---------------------------------------------------------------------------
// Per-patch epilogue: stage the patch's contiguous [SPLITK][HID] bf16 partials
// into LDS (coalesced 16B loads), sum + bias -> norm -> 21 dots ->
// masked exp(2*sim) -> partial[p].  (Global reduce stays a separate tiny
// kernel: 2048 same-address device atomics cost ~40us — measured round 1.)
// ---------------------------------------------------------------------------
template <int SPLITK>
__global__ __launch_bounds__(256) void k_final(const ushort* __restrict__ pbuf,
                                               const float* __restrict__ conv_b,
                                               const float* __restrict__ classlat,
                                               const int* __restrict__ mask,
                                               float* __restrict__ partial) {
    const int p = blockIdx.x;        // 0..2047
    const int b = p >> 10, n = p & 1023;
    const int t = threadIdx.x;
    const int lane = t & 63, wv = t >> 6;

    __shared__ ushort sh[SPLITK * HID];
    const ushort* pb = pbuf + (size_t)p * (SPLITK * HID);
    for (int i = t; i < SPLITK * HID / 8; i += 256)
        *(short8*)&sh[i * 8] = *(const short8*)&pb[(size_t)i * 8];
    __syncthreads();

    float f0 = conv_b[t], f1 = conv_b[t + 256], f2 = conv_b[t + 512];
#pragma unroll
    for (int z = 0; z < SPLITK; ++z) {
        f0 += bf2f(sh[z * HID + t]);
        f1 += bf2f(sh[z * HID + t + 256]);
        f2 += bf2f(sh[z * HID + t + 512]);
    }

    __shared__ float wsum[4];
    __shared__ float wdot[4][NCLS];
    __shared__ float cpart[NCLS];

    float ss = f0 * f0 + f1 * f1 + f2 * f2;
#pragma unroll
    for (int off = 32; off >= 1; off >>= 1) ss += __shfl_xor(ss, off, 64);
    if (lane == 0) wsum[wv] = ss;

    float dots[NCLS];
#pragma unroll
    for (int c = 0; c < NCLS; ++c) {
        const float* cl = classlat + c * HID;
        dots[c] = cl[t] * f0 + cl[t + 256] * f1 + cl[t + 512] * f2;
    }
#pragma unroll
    for (int c = 0; c < NCLS; ++c) {
        float v = dots[c];
#pragma unroll
        for (int off = 32; off >= 1; off >>= 1) v += __shfl_xor(v, off, 64);
        if (lane == 0) wdot[wv][c] = v;
    }
    __syncthreads();

    if (t < NCLS) {
        float tot  = wsum[0] + wsum[1] + wsum[2] + wsum[3];
        float invn = 1.0f / sqrtf(tot);
        float dot  = wdot[0][t] + wdot[1][t] + wdot[2][t] + wdot[3][t];
        float sim  = dot * invn;
        int   mv   = mask[(size_t)(b * NCLS + t) * NPATCH + n];
        cpart[t]   = (mv != 0) ? expf(sim * 2.0f) : 0.0f;
    }
    __syncthreads();
    if (t == 0) {
        float s = 0.f;
#pragma unroll
        for (int c = 0; c < NCLS; ++c) s += cpart[c];
        partial[p] = s;
    }
}

__global__ __launch_bounds__(256) void k_reduce(const float* __restrict__ partial,
                                                float* __restrict__ out) {
    int t = threadIdx.x;
    float s = 0.f;
    for (int i = t; i < NP; i += 256) s += partial[i];
#pragma unroll
    for (int off = 32; off >= 1; off >>= 1) s += __shfl_xor(s, off, 64);
    __shared__ float ws[4];
    if ((t & 63) == 0) ws[t >> 6] = s;
    __syncthreads();
    if (t == 0) out[0] = -logf(ws[0] + ws[1] + ws[2] + ws[3]);
}

// ---------------------------------------------------------------------------
extern "C" void kernel_launch(void* const* d_in, const int* in_sizes, int n_in,
                              void* d_out, int out_size, void* d_ws, size_t ws_size,
                              hipStream_t stream) {
    const float* x      = (const float*)d_in[0];
    const int*   mask   = (const int*)d_in[1];
    const float* conv_w = (const float*)d_in[2];
    const float* conv_b = (const float*)d_in[3];
    const float* latent = (const float*)d_in[4];
    float* out = (float*)d_out;

    // workspace layout (bytes)
    const size_t xb_bytes   = (size_t)NP * KDIM * 2;        // 33,554,432
    const size_t wb_bytes   = (size_t)HID * KDIM * 2;       // 12,582,912
    const size_t pslice     = (size_t)NP * HID * 2;         // 3,145,728 (bf16)
    const size_t small_need = (size_t)NCLS * HID * 4 + NP * 4 + 256;

    char* base = (char*)d_ws;
    ushort* xb   = (ushort*)base;
    ushort* wb   = (ushort*)(base + xb_bytes);
    ushort* pbuf = (ushort*)(base + xb_bytes + wb_bytes);

    int splitk = 1;
    const size_t fixed = xb_bytes + wb_bytes + small_need;
    if (ws_size >= fixed + 8 * pslice)      splitk = 8;
    else if (ws_size >= fixed + 4 * pslice) splitk = 4;
    else if (ws_size >= fixed + 2 * pslice) splitk = 2;

    float* classlat = (float*)(base + xb_bytes + wb_bytes + (size_t)splitk * pslice);
    float* partial  = classlat + NCLS * HID;

    k_prep<<<NB_W4 + NB_XT + NCLS, 256, 0, stream>>>(conv_w, x, latent, wb, xb, classlat);

    dim3 g(NP / 128, HID / 128, splitk);
    switch (splitk) {
        case 8: k_gemm<8><<<g, 256, 0, stream>>>(xb, wb, pbuf); break;
        case 4: k_gemm<4><<<g, 256, 0, stream>>>(xb, wb, pbuf); break;
        case 2: k_gemm<2><<<g, 256, 0, stream>>>(xb, wb, pbuf); break;
        default: k_gemm<1><<<g, 256, 0, stream>>>(xb, wb, pbuf); break;
    }

    switch (splitk) {
        case 8: k_final<8><<<NP, 256, 0, stream>>>(pbuf, conv_b, classlat, mask, partial); break;
        case 4: k_final<4><<<NP, 256, 0, stream>>>(pbuf, conv_b, classlat, mask, partial); break;
        case 2: k_final<2><<<NP, 256, 0, stream>>>(pbuf, conv_b, classlat, mask, partial); break;
        default: k_final<1><<<NP, 256, 0, stream>>>(pbuf, conv_b, classlat, mask, partial); break;
    }
    k_reduce<<<1, 256, 0, stream>>>(partial, out);
}

// Round 4
// 85.247 us; speedup vs baseline: 1.6900x; 1.1243x over previous
//
#include <hip/hip_runtime.h>
#include <math.h>

// Problem constants
#define B_     2
#define CIN    32
#define HH     512
#define WW     512
#define HID    768
#define SZ     16
#define NPATCH 1024      // 32x32 patch grid
#define KDIM   8192      // CIN*SZ*SZ
#define NCLS   21
#define LAT    128
#define LC     2688      // LAT*NCLS
#define NP     (B_ * NPATCH)   // 2048 patch rows

// prep-kernel block ranges (classlat FIRST so it overlaps the bulk,
// instead of trailing it — round-3 tail cost ~20us of near-idle machine)
#define NB_CL  63        // NCLS*3 : classlat (cls, 256-wide d-segment)
#define NB_W4  1536      // HID*KDIM/16/256  (4 float4 per thread)
#define NB_XT  2048      // B_*CIN*(HH/16)   one block per (b,c,ph) = 32KB chunk

typedef __attribute__((ext_vector_type(8))) short short8;   // 8 bf16 (4 VGPR)
typedef __attribute__((ext_vector_type(4))) float f32x4;

// RNE float->bf16
__device__ __forceinline__ ushort f2bf(float f) {
    union { float f; unsigned u; } v; v.f = f;
    unsigned r = (v.u + 0x7fff + ((v.u >> 16) & 1)) >> 16;
    return (ushort)r;
}
__device__ __forceinline__ float bf2f(ushort u) {
    union { unsigned u; float f; } v; v.u = (unsigned)u << 16;
    return v.f;
}

__device__ __forceinline__ void gload16(const void* g, void* l) {
    __builtin_amdgcn_global_load_lds(
        (const __attribute__((address_space(1))) unsigned int*)g,
        (__attribute__((address_space(3))) unsigned int*)l, 16, 0, 0);
}

// ---------------------------------------------------------------------------
// Row scales: scale[l] = 1 / (128 * ||lat_l||).  One wave per row, 672 blocks
// (round-0 verified k_rowscale).  Runs before k_prep so classlat blocks can
// consume scales immediately.
// ---------------------------------------------------------------------------
__global__ __launch_bounds__(256) void k_scale(const float* __restrict__ lat,
                                               float* __restrict__ scale) {
    int wid  = blockIdx.x * 4 + (threadIdx.x >> 6);
    int lane = threadIdx.x & 63;
    const float* row = lat + (size_t)wid * HID;
    float s = 0.f;
#pragma unroll
    for (int q = 0; q < HID / 64; ++q) {
        float v = row[lane + q * 64];
        s += v * v;
    }
#pragma unroll
    for (int off = 32; off >= 1; off >>= 1) s += __shfl_xor(s, off, 64);
    if (lane == 0) scale[wid] = 1.0f / (128.0f * sqrtf(s));
}

// ---------------------------------------------------------------------------
// Fused prep kernel:
//   blocks [0, NB_CL)       : classlat[cls][dseg*256+t] = sum_u lat[u*21+cls][.]*scale
//                             (63 parallel blocks, 8-deep load batching, runs
//                             concurrently with the bulk)
//   blocks [.., +NB_W4)     : conv_w f32 -> bf16, explicit 4-deep load batch
//   blocks [.., +NB_XT)     : x -> bf16 patch-major via LDS transpose,
//                             explicit 8-deep load batch (round-3's VGPR=28
//                             showed the compiler serialized loads 1-deep)
// ---------------------------------------------------------------------------
__global__ __launch_bounds__(256) void k_prep(const float* __restrict__ w,
                                              const float* __restrict__ x,
                                              const float* __restrict__ lat,
                                              const float* __restrict__ scale,
                                              ushort* __restrict__ wb,
                                              ushort* __restrict__ xb,
                                              float* __restrict__ classlat) {
    const int bid = blockIdx.x;
    const int t   = threadIdx.x;

    if (bid < NB_CL) {
        // ---- classlat accumulation (norms precomputed by k_scale) ----
        const int cls  = bid / 3;
        const int dseg = bid % 3;
        __shared__ float sc_sh[LAT];
        if (t < LAT) sc_sh[t] = scale[t * NCLS + cls];
        __syncthreads();

        const float* src = lat + (size_t)cls * HID + dseg * 256 + t;
        float a = 0.f;
        for (int u0 = 0; u0 < LAT; u0 += 8) {
            float v[8];
#pragma unroll
            for (int q = 0; q < 8; ++q)
                v[q] = src[(size_t)(u0 + q) * (NCLS * HID)];
#pragma unroll
            for (int q = 0; q < 8; ++q) a += v[q] * sc_sh[u0 + q];
        }
        classlat[cls * HID + dseg * 256 + t] = a;
    } else if (bid < NB_CL + NB_W4) {
        // ---- conv_w convert (coalesced both sides, 4 loads in flight) ----
        const int cb = bid - NB_CL;
        float4 vv[4];
#pragma unroll
        for (int k = 0; k < 4; ++k)
            vv[k] = *(const float4*)(w + ((size_t)cb * 1024 + k * 256 + t) * 4);
#pragma unroll
        for (int k = 0; k < 4; ++k) {
            ushort4 o;
            o.x = f2bf(vv[k].x); o.y = f2bf(vv[k].y);
            o.z = f2bf(vv[k].z); o.w = f2bf(vv[k].w);
            *(ushort4*)(wb + ((size_t)cb * 1024 + k * 256 + t) * 4) = o;
        }
    } else {
        // ---- x convert via LDS transpose (8 loads in flight) ----
        __shared__ ushort sh[32 * 264];   // [pw][256+8 pad]
        const int cvb = bid - (NB_CL + NB_W4);
        const int b  = cvb >> 10;
        const int c  = (cvb >> 5) & 31;
        const int ph = cvb & 31;
        const float* src = x + (((size_t)(b * CIN + c) * HH) + (size_t)ph * 16) * WW;

        float4 vv[8];
#pragma unroll
        for (int q = 0; q < 8; ++q) {
            int f  = q * 256 + t;        // [0, 2048) = 16 rows x 128 float4
            int i  = f >> 7;
            int w4 = f & 127;
            vv[q] = *(const float4*)(src + (size_t)i * WW + w4 * 4);
        }
#pragma unroll
        for (int q = 0; q < 8; ++q) {
            int f  = q * 256 + t;
            int i  = f >> 7;
            int w4 = f & 127;
            int pw = w4 >> 2, j0 = (w4 & 3) * 4;
            ushort4 o;
            o.x = f2bf(vv[q].x); o.y = f2bf(vv[q].y);
            o.z = f2bf(vv[q].z); o.w = f2bf(vv[q].w);
            *(ushort4*)&sh[pw * 264 + i * 16 + j0] = o;
        }
        __syncthreads();

        // write out: 32 patches x 256 elems (512B dense segments)
        ushort* dst = xb + ((size_t)(b * 1024 + ph * 32) << 13) + c * 256;
        short8 rv[4];
#pragma unroll
        for (int q = 0; q < 4; ++q) {
            int s  = q * 256 + t;
            int pw = s >> 5;
            int o8 = (s & 31) * 8;
            rv[q] = *(const short8*)&sh[pw * 264 + o8];
        }
#pragma unroll
        for (int q = 0; q < 4; ++q) {
            int s  = q * 256 + t;
            int pw = s >> 5;
            int o8 = (s & 31) * 8;
            *(short8*)&dst[((size_t)pw << 13) + o8] = rv[q];
        }
    }
}

// ---------------------------------------------------------------------------
// MFMA GEMM: patch[p][d] = sum_k xb[p][k] * wb[d][k]   (B^T layout)
// 128x128 tile, BK=64, 4 waves (2x2) each 64x64 via 4x4 mfma_f32_16x16x32_bf16.
// T2 XOR swizzle (rule #21): linear LDS dest + inverse-swizzled global source
// + swizzled ds_read.  T1 bijective XCD remap: each XCD owns one split-K slice.
// Output layout: pbuf[p][z][d]  (per-patch split-K partials contiguous)
// ---------------------------------------------------------------------------
template <int SPLITK>
__global__ __launch_bounds__(256) void k_gemm(const ushort* __restrict__ xb,
                                              const ushort* __restrict__ wb,
                                              ushort* __restrict__ pbuf) {
    constexpr int KS = KDIM / SPLITK;
    __shared__ ushort Als[128 * 64];   // [row][k] row-major, 16 KB
    __shared__ ushort Bls[128 * 64];

    // ---- T1 remap ----
    const int flat = blockIdx.x + 16 * (blockIdx.y + 6 * blockIdx.z);
    constexpr int nwg = 96 * SPLITK;
    const int wg = (flat & 7) * (nwg >> 3) + (flat >> 3);
    const int bz = wg / 96;
    const int rr = wg - bz * 96;
    const int by = rr % 6;
    const int bx = rr / 6;

    const int tid  = threadIdx.x;
    const int wv   = tid >> 6;
    const int lane = tid & 63;
    const int wm   = (wv >> 1) * 64;
    const int wn   = (wv & 1) * 64;

    const size_t abase = ((size_t)bx * 128) * KDIM + (size_t)bz * KS;
    const size_t bbase = ((size_t)by * 128) * KDIM + (size_t)bz * KS;

    const int srow  = wv * 8 + (lane >> 3);                    // + q*32
    const int skoff = (((lane & 7) ^ (lane >> 3)) * 8);        // swizzled source elem

    f32x4 acc[4][4];
#pragma unroll
    for (int m = 0; m < 4; ++m)
#pragma unroll
        for (int n = 0; n < 4; ++n) acc[m][n] = (f32x4)(0.f);

    const int fr = lane & 15, fq = lane >> 4;
    const int frx = (fr & 7) * 8;   // read-side XOR (elements)

    for (int kk = 0; kk < KS; kk += 64) {
#pragma unroll
        for (int q = 0; q < 4; ++q) {
            const int row = q * 32 + srow;
            gload16(&xb[abase + (size_t)row * KDIM + kk + skoff], &Als[q * 2048 + wv * 512]);
            gload16(&wb[bbase + (size_t)row * KDIM + kk + skoff], &Bls[q * 2048 + wv * 512]);
        }
        __syncthreads();   // drains vmcnt: tiles ready

#pragma unroll
        for (int s = 0; s < 2; ++s) {
            short8 af[4], bf[4];
#pragma unroll
            for (int m = 0; m < 4; ++m)
                af[m] = *(const short8*)&Als[(wm + m * 16 + fr) * 64 + ((s * 32 + fq * 8) ^ frx)];
#pragma unroll
            for (int n = 0; n < 4; ++n)
                bf[n] = *(const short8*)&Bls[(wn + n * 16 + fr) * 64 + ((s * 32 + fq * 8) ^ frx)];
#pragma unroll
            for (int m = 0; m < 4; ++m)
#pragma unroll
                for (int n = 0; n < 4; ++n)
                    acc[m][n] = __builtin_amdgcn_mfma_f32_16x16x32_bf16(af[m], bf[n], acc[m][n], 0, 0, 0);
        }
        __syncthreads();
    }

#pragma unroll
    for (int m = 0; m < 4; ++m) {
#pragma unroll
        for (int n = 0; n < 4; ++n) {
            int col = by * 128 + wn + n * 16 + fr;
#pragma unroll
            for (int j = 0; j < 4; ++j) {
                int row = bx * 128 + wm + m * 16 + fq * 4 + j;
                pbuf[((size_t)row * SPLITK + bz) * HID + col] = f2bf(acc[m][n][j]);
            }
        }
    }
}

// ---------------------------------------------------------------------------
// Per-patch epilogue: stage the patch's contiguous [SPLITK][HID] bf16 partials
// into LDS (coalesced 16B loads), sum + bias -> norm -> 21 dots ->
// masked exp(2*sim) -> partial[p].  (Global reduce stays a separate tiny
// kernel: 2048 same-address device atomics cost ~40us — measured round 1.)
// ---------------------------------------------------------------------------
template <int SPLITK>
__global__ __launch_bounds__(256) void k_final(const ushort* __restrict__ pbuf,
                                               const float* __restrict__ conv_b,
                                               const float* __restrict__ classlat,
                                               const int* __restrict__ mask,
                                               float* __restrict__ partial) {
    const int p = blockIdx.x;        // 0..2047
    const int b = p >> 10, n = p & 1023;
    const int t = threadIdx.x;
    const int lane = t & 63, wv = t >> 6;

    __shared__ ushort sh[SPLITK * HID];
    const ushort* pb = pbuf + (size_t)p * (SPLITK * HID);
    for (int i = t; i < SPLITK * HID / 8; i += 256)
        *(short8*)&sh[i * 8] = *(const short8*)&pb[(size_t)i * 8];
    __syncthreads();

    float f0 = conv_b[t], f1 = conv_b[t + 256], f2 = conv_b[t + 512];
#pragma unroll
    for (int z = 0; z < SPLITK; ++z) {
        f0 += bf2f(sh[z * HID + t]);
        f1 += bf2f(sh[z * HID + t + 256]);
        f2 += bf2f(sh[z * HID + t + 512]);
    }

    __shared__ float wsum[4];
    __shared__ float wdot[4][NCLS];
    __shared__ float cpart[NCLS];

    float ss = f0 * f0 + f1 * f1 + f2 * f2;
#pragma unroll
    for (int off = 32; off >= 1; off >>= 1) ss += __shfl_xor(ss, off, 64);
    if (lane == 0) wsum[wv] = ss;

    float dots[NCLS];
#pragma unroll
    for (int c = 0; c < NCLS; ++c) {
        const float* cl = classlat + c * HID;
        dots[c] = cl[t] * f0 + cl[t + 256] * f1 + cl[t + 512] * f2;
    }
#pragma unroll
    for (int c = 0; c < NCLS; ++c) {
        float v = dots[c];
#pragma unroll
        for (int off = 32; off >= 1; off >>= 1) v += __shfl_xor(v, off, 64);
        if (lane == 0) wdot[wv][c] = v;
    }
    __syncthreads();

    if (t < NCLS) {
        float tot  = wsum[0] + wsum[1] + wsum[2] + wsum[3];
        float invn = 1.0f / sqrtf(tot);
        float dot  = wdot[0][t] + wdot[1][t] + wdot[2][t] + wdot[3][t];
        float sim  = dot * invn;
        int   mv   = mask[(size_t)(b * NCLS + t) * NPATCH + n];
        cpart[t]   = (mv != 0) ? expf(sim * 2.0f) : 0.0f;
    }
    __syncthreads();
    if (t == 0) {
        float s = 0.f;
#pragma unroll
        for (int c = 0; c < NCLS; ++c) s += cpart[c];
        partial[p] = s;
    }
}

__global__ __launch_bounds__(256) void k_reduce(const float* __restrict__ partial,
                                                float* __restrict__ out) {
    int t = threadIdx.x;
    float s = 0.f;
    for (int i = t; i < NP; i += 256) s += partial[i];
#pragma unroll
    for (int off = 32; off >= 1; off >>= 1) s += __shfl_xor(s, off, 64);
    __shared__ float ws[4];
    if ((t & 63) == 0) ws[t >> 6] = s;
    __syncthreads();
    if (t == 0) out[0] = -logf(ws[0] + ws[1] + ws[2] + ws[3]);
}

// ---------------------------------------------------------------------------
extern "C" void kernel_launch(void* const* d_in, const int* in_sizes, int n_in,
                              void* d_out, int out_size, void* d_ws, size_t ws_size,
                              hipStream_t stream) {
    const float* x      = (const float*)d_in[0];
    const int*   mask   = (const int*)d_in[1];
    const float* conv_w = (const float*)d_in[2];
    const float* conv_b = (const float*)d_in[3];
    const float* latent = (const float*)d_in[4];
    float* out = (float*)d_out;

    // workspace layout (bytes)
    const size_t xb_bytes   = (size_t)NP * KDIM * 2;        // 33,554,432
    const size_t wb_bytes   = (size_t)HID * KDIM * 2;       // 12,582,912
    const size_t pslice     = (size_t)NP * HID * 2;         // 3,145,728 (bf16)
    const size_t small_need = (size_t)NCLS * HID * 4 + NP * 4 + LC * 4 + 256;

    char* base = (char*)d_ws;
    ushort* xb   = (ushort*)base;
    ushort* wb   = (ushort*)(base + xb_bytes);
    ushort* pbuf = (ushort*)(base + xb_bytes + wb_bytes);

    int splitk = 1;
    const size_t fixed = xb_bytes + wb_bytes + small_need;
    if (ws_size >= fixed + 8 * pslice)      splitk = 8;
    else if (ws_size >= fixed + 4 * pslice) splitk = 4;
    else if (ws_size >= fixed + 2 * pslice) splitk = 2;

    float* classlat = (float*)(base + xb_bytes + wb_bytes + (size_t)splitk * pslice);
    float* partial  = classlat + NCLS * HID;
    float* scale    = partial + NP;

    k_scale<<<LC / 4, 256, 0, stream>>>(latent, scale);
    k_prep<<<NB_CL + NB_W4 + NB_XT, 256, 0, stream>>>(conv_w, x, latent, scale,
                                                      wb, xb, classlat);

    dim3 g(NP / 128, HID / 128, splitk);
    switch (splitk) {
        case 8: k_gemm<8><<<g, 256, 0, stream>>>(xb, wb, pbuf); break;
        case 4: k_gemm<4><<<g, 256, 0, stream>>>(xb, wb, pbuf); break;
        case 2: k_gemm<2><<<g, 256, 0, stream>>>(xb, wb, pbuf); break;
        default: k_gemm<1><<<g, 256, 0, stream>>>(xb, wb, pbuf); break;
    }

    switch (splitk) {
        case 8: k_final<8><<<NP, 256, 0, stream>>>(pbuf, conv_b, classlat, mask, partial); break;
        case 4: k_final<4><<<NP, 256, 0, stream>>>(pbuf, conv_b, classlat, mask, partial); break;
        case 2: k_final<2><<<NP, 256, 0, stream>>>(pbuf, conv_b, classlat, mask, partial); break;
        default: k_final<1><<<NP, 256, 0, stream>>>(pbuf, conv_b, classlat, mask, partial); break;
    }
    k_reduce<<<1, 256, 0, stream>>>(partial, out);
}